// Round 2
// baseline (446.607 us; speedup 1.0000x reference)
//
#include <hip/hip_runtime.h>
#include <hip/hip_bf16.h>

// ---------- helpers ----------

__device__ __forceinline__ unsigned short f2bf(float f) {
    unsigned u = __float_as_uint(f);
    unsigned r = u + 0x7fffu + ((u >> 16) & 1u);
    return (unsigned short)(r >> 16);
}

typedef __bf16 bf16_t;
typedef bf16_t bf16x8 __attribute__((ext_vector_type(8)));
typedef float f32x4 __attribute__((ext_vector_type(4)));

typedef const __attribute__((address_space(1))) unsigned int* gptr_t;
typedef __attribute__((address_space(3))) unsigned int* lptr_t;

__device__ __forceinline__ void gload_lds16(const void* g, void* l) {
    __builtin_amdgcn_global_load_lds((gptr_t)g, (lptr_t)l, 16, 0, 0);
}

// ---------- kernel 1: column-wise max of |x| ----------
__global__ void colmax_kernel(const float* __restrict__ src, int rows, int cols,
                              unsigned int* __restrict__ dst, int rows_per_block) {
    int c = (blockIdx.x * blockDim.x + threadIdx.x) * 4;
    if (c >= cols) return;
    int r0 = blockIdx.y * rows_per_block;
    int r1 = min(r0 + rows_per_block, rows);
    float m0 = 0.f, m1 = 0.f, m2 = 0.f, m3 = 0.f;
    const float* p = src + (size_t)r0 * cols + c;
    for (int r = r0; r < r1; ++r, p += cols) {
        float4 v = *(const float4*)p;
        m0 = fmaxf(m0, fabsf(v.x));
        m1 = fmaxf(m1, fabsf(v.y));
        m2 = fmaxf(m2, fabsf(v.z));
        m3 = fmaxf(m3, fabsf(v.w));
    }
    atomicMax(dst + c + 0, __float_as_uint(m0));
    atomicMax(dst + c + 1, __float_as_uint(m1));
    atomicMax(dst + c + 2, __float_as_uint(m2));
    atomicMax(dst + c + 3, __float_as_uint(m3));
}

// ---------- kernel 1b: fused column-max of |W| + W -> bf16 ----------
__global__ void wmaxconv_kernel(const float* __restrict__ W, unsigned int* __restrict__ mw,
                                unsigned short* __restrict__ Wb, int rows, int cols,
                                int rows_per_block) {
    int c = (blockIdx.x * blockDim.x + threadIdx.x) * 4;
    if (c >= cols) return;
    int r0 = blockIdx.y * rows_per_block;
    int r1 = min(r0 + rows_per_block, rows);
    float m0 = 0.f, m1 = 0.f, m2 = 0.f, m3 = 0.f;
    const float* p = W + (size_t)r0 * cols + c;
    unsigned short* q = Wb + (size_t)r0 * cols + c;
    for (int r = r0; r < r1; ++r, p += cols, q += cols) {
        float4 v = *(const float4*)p;
        ushort4 o;
        o.x = f2bf(v.x); o.y = f2bf(v.y); o.z = f2bf(v.z); o.w = f2bf(v.w);
        *(ushort4*)q = o;
        m0 = fmaxf(m0, fabsf(v.x));
        m1 = fmaxf(m1, fabsf(v.y));
        m2 = fmaxf(m2, fabsf(v.z));
        m3 = fmaxf(m3, fabsf(v.w));
    }
    atomicMax(mw + c + 0, __float_as_uint(m0));
    atomicMax(mw + c + 1, __float_as_uint(m1));
    atomicMax(mw + c + 2, __float_as_uint(m2));
    atomicMax(mw + c + 3, __float_as_uint(m3));
}

// ---------- kernel 2: s = sqrt(max_act / clip(max_w, EPS)) ----------
__global__ void s_kernel(const unsigned int* __restrict__ ma,
                         const unsigned int* __restrict__ mw,
                         float* __restrict__ s, int n) {
    int i = blockIdx.x * blockDim.x + threadIdx.x;
    if (i < n) {
        float a = __uint_as_float(ma[i]);
        float w = fmaxf(__uint_as_float(mw[i]), 1e-8f);
        s[i] = sqrtf(a / w);
    }
}

// ---------- kernel 3: 2:4 prune of (x/s), emit bf16(x)*mask ----------
__global__ void prune_kernel(const float* __restrict__ x, const float* __restrict__ s,
                             unsigned short* __restrict__ xsp, size_t ngroups, int cols) {
    size_t g = (size_t)blockIdx.x * blockDim.x + threadIdx.x;
    size_t stride = (size_t)gridDim.x * blockDim.x;
    for (; g < ngroups; g += stride) {
        size_t e = g * 4;
        int cb = (int)(e & (size_t)(cols - 1));
        float4 v = *(const float4*)(x + e);
        float4 sv = *(const float4*)(s + cb);
        float a0 = fabsf(v.x / sv.x);
        float a1 = fabsf(v.y / sv.y);
        float a2 = fabsf(v.z / sv.z);
        float a3 = fabsf(v.w / sv.w);
        int r0 = 0, r1 = 0, r2 = 0, r3 = 0;
        if (a1 > a0) r0++; else r1++;
        if (a2 > a0) r0++; else r2++;
        if (a3 > a0) r0++; else r3++;
        if (a2 > a1) r1++; else r2++;
        if (a3 > a1) r1++; else r3++;
        if (a3 > a2) r2++; else r3++;
        ushort4 o;
        o.x = (r0 < 2) ? f2bf(v.x) : (unsigned short)0;
        o.y = (r1 < 2) ? f2bf(v.y) : (unsigned short)0;
        o.z = (r2 < 2) ? f2bf(v.z) : (unsigned short)0;
        o.w = (r3 < 2) ? f2bf(v.w) : (unsigned short)0;
        *(ushort4*)(xsp + e) = o;
    }
}

// ---------- kernel 5: 256x256 8-phase bf16 B^T GEMM ----------
// C[m,n] = sum_k A[m,k]*B[n,k]. 8 waves (2Mx4N), BK=64, 128 KiB LDS dbuf,
// XOR swizzle byte^=(row&7)<<4 (read side + pre-swizzled global source),
// counted vmcnt(4) once per K-tile, setprio around MFMA clusters.

// stage one 128-row half-tile (2 global_load_lds_dwordx4 per wave).
// ISB: 0=A (half = rows with bit6==H), 1=B (half = rows with bit5==H).
template <int ISB, int H>
__device__ __forceinline__ void stage_half(const unsigned short* __restrict__ G, int ldk,
                                           long blockBase, int k0, unsigned short* sbuf,
                                           int wid, int l) {
#pragma unroll
    for (int j = 0; j < 2; ++j) {
        int rho0;
        if (ISB) rho0 = ((wid * 8) & 31) + (wid >> 2) * 64 + H * 32 + j * 128;
        else     rho0 = wid * 8 + H * 64 + j * 128;
        int rho = rho0 + (l >> 3);
        int c = l & 7;
        const unsigned short* src =
            G + (size_t)(blockBase + rho) * ldk + k0 + ((c ^ (rho & 7)) << 3);
        gload_lds16(src, (char*)sbuf + rho0 * 128);
    }
}

#define STAGE_A0(k, buf) stage_half<0, 0>(A, K, browBase, (k), (buf), wid, l)
#define STAGE_A1(k, buf) stage_half<0, 1>(A, K, browBase, (k), (buf), wid, l)
#define STAGE_B0(k, buf) stage_half<1, 0>(B, K, bcolBase, (k), (buf), wid, l)
#define STAGE_B1(k, buf) stage_half<1, 1>(B, K, bcolBase, (k), (buf), wid, l)

#define PHASE(MH, NH, STAGE, WAITV)                                                     \
    {                                                                                   \
        bf16x8 af[4][2], bv[2][2];                                                      \
        int ar = wr * 128 + (MH) * 64 + (l & 15);                                       \
        int br = wc * 64 + (NH) * 32 + (l & 15);                                        \
        int clb = l >> 4;                                                               \
        _Pragma("unroll") for (int mm = 0; mm < 4; ++mm)                                \
            _Pragma("unroll") for (int kk = 0; kk < 2; ++kk) {                          \
            int row = ar + mm * 16, cl = kk * 4 + clb;                                  \
            af[mm][kk] = *(const bf16x8*)((const char*)curA + row * 128 +               \
                                          ((cl ^ (row & 7)) << 4));                     \
        }                                                                               \
        _Pragma("unroll") for (int nn = 0; nn < 2; ++nn)                                \
            _Pragma("unroll") for (int kk = 0; kk < 2; ++kk) {                          \
            int row = br + nn * 16, cl = kk * 4 + clb;                                  \
            bv[nn][kk] = *(const bf16x8*)((const char*)curB + row * 128 +               \
                                          ((cl ^ (row & 7)) << 4));                     \
        }                                                                               \
        STAGE;                                                                          \
        WAITV;                                                                          \
        __builtin_amdgcn_s_barrier();                                                   \
        asm volatile("s_waitcnt lgkmcnt(0)" ::: "memory");                              \
        __builtin_amdgcn_sched_barrier(0);                                              \
        __builtin_amdgcn_s_setprio(1);                                                  \
        _Pragma("unroll") for (int mm = 0; mm < 4; ++mm)                                \
            _Pragma("unroll") for (int nn = 0; nn < 2; ++nn)                            \
                _Pragma("unroll") for (int kk = 0; kk < 2; ++kk)                        \
            acc[(MH) * 4 + mm][(NH) * 2 + nn] = __builtin_amdgcn_mfma_f32_16x16x32_bf16(\
                af[mm][kk], bv[nn][kk], acc[(MH) * 4 + mm][(NH) * 2 + nn], 0, 0, 0);    \
        __builtin_amdgcn_s_setprio(0);                                                  \
        __builtin_amdgcn_s_barrier();                                                   \
        asm volatile("" ::: "memory");                                                  \
        __builtin_amdgcn_sched_barrier(0);                                              \
    }

__global__ __launch_bounds__(512, 2) void gemm_bt256(
        const unsigned short* __restrict__ A,
        const unsigned short* __restrict__ B,
        float* __restrict__ C, int M, int N, int K) {
    __shared__ unsigned short sA[2][256 * 64];
    __shared__ unsigned short sB[2][256 * 64];
    const int tid = threadIdx.x;
    const int l = tid & 63;
    const int wid = tid >> 6;
    const int wr = wid >> 2;
    const int wc = wid & 3;

    // bijective XCD swizzle; by-fastest so each XCD's B-panels fit its L2
    const int nbx = N >> 8, nby = M >> 8;
    const int nwg = nbx * nby;
    const int cpx = nwg >> 3;
    const int swz = ((int)blockIdx.x & 7) * cpx + ((int)blockIdx.x >> 3);
    const int by = swz % nby;
    const int bx = swz / nby;
    const long browBase = (long)by << 8;
    const long bcolBase = (long)bx << 8;

    const int NT = K >> 6;

    f32x4 acc[8][4] = {};

    // prologue: tile0 fully + tile1's A_h0,B_h1
    STAGE_A0(0, sA[0]);
    STAGE_A1(0, sA[0]);
    STAGE_B0(0, sB[0]);
    STAGE_B1(0, sB[0]);
    STAGE_A0(64, sA[1]);
    STAGE_B1(64, sB[1]);
    asm volatile("s_waitcnt vmcnt(4)" ::: "memory");
    __builtin_amdgcn_s_barrier();
    asm volatile("" ::: "memory");
    __builtin_amdgcn_sched_barrier(0);

    for (int t = 0; t < NT; ++t) {
        const int cur = t & 1;
        const unsigned short* curA = sA[cur];
        const unsigned short* curB = sB[cur];
        unsigned short* nxA = sA[cur ^ 1];
        unsigned short* nxB = sB[cur ^ 1];
        unsigned short* wAc = sA[cur];
        unsigned short* wBc = sB[cur];
        const int k1 = (t + 1) << 6;
        const int k2 = (t + 2) << 6;
        const bool s1 = (t + 1) < NT;
        const bool s2 = (t + 2) < NT;

        // p1: quadrant (0,0); stage A_h1(t+1), B_h0(t+1) into other buffer
        PHASE(0, 0, { if (s1) { STAGE_A1(k1, nxA); STAGE_B0(k1, nxB); } }, );
        // p2: quadrant (0,1); no stage
        PHASE(0, 1, {}, );
        // p3: quadrant (1,1); stage A_h0(t+2) into current buffer (region free)
        PHASE(1, 1, { if (s2) { STAGE_A0(k2, wAc); } }, );
        // p4: quadrant (1,0); stage B_h1(t+2); counted vmcnt covers tile t+1
        PHASE(1, 0, { if (s2) { STAGE_B1(k2, wBc); } },
              asm volatile("s_waitcnt vmcnt(4)" ::: "memory"));
    }

    // epilogue: C/D layout col = lane&15, row = (lane>>4)*4 + reg
    const int er = (l >> 4) * 4;
    const int ec = l & 15;
#pragma unroll
    for (int mm = 0; mm < 8; ++mm) {
#pragma unroll
        for (int nn = 0; nn < 4; ++nn) {
            long row = browBase + wr * 128 + mm * 16 + er;
            long col = bcolBase + wc * 64 + nn * 16 + ec;
            float* cp = C + row * N + col;
#pragma unroll
            for (int r = 0; r < 4; ++r)
                cp[(long)r * N] = acc[mm][nn][r];
        }
    }
}

// ---------- launch ----------
extern "C" void kernel_launch(void* const* d_in, const int* in_sizes, int n_in,
                              void* d_out, int out_size, void* d_ws, size_t ws_size,
                              hipStream_t stream) {
    const float* x = (const float*)d_in[0];
    const float* W = (const float*)d_in[1];
    float* out = (float*)d_out;

    const int K = 4096;
    const int Nout = in_sizes[1] / K;             // 4096
    const size_t Mrows = (size_t)in_sizes[0] / K; // 8192

    char* ws = (char*)d_ws;
    unsigned short* Xsp = (unsigned short*)ws;
    unsigned short* Wb = (unsigned short*)(ws + Mrows * K * 2);
    unsigned int* ma = (unsigned int*)(ws + Mrows * K * 2 + (size_t)Nout * K * 2);
    unsigned int* mw = ma + K;
    float* s = (float*)(mw + K);

    hipMemsetAsync(ma, 0, 2 * K * sizeof(unsigned int), stream);

    dim3 blk(256);
    {
        dim3 gx(K / 1024, (unsigned)(Mrows / 64));
        colmax_kernel<<<gx, blk, 0, stream>>>(x, (int)Mrows, K, ma, 64);
        dim3 gw(K / 1024, Nout / 64);
        wmaxconv_kernel<<<gw, blk, 0, stream>>>(W, mw, Wb, Nout, K, 64);
    }
    s_kernel<<<dim3((K + 255) / 256), blk, 0, stream>>>(ma, mw, s, K);
    {
        size_t ngroups = Mrows * K / 4;
        prune_kernel<<<dim3(2048), blk, 0, stream>>>(x, s, Xsp, ngroups, K);
    }
    {
        dim3 g((unsigned)((Mrows / 256) * (Nout / 256)));
        gemm_bt256<<<g, dim3(512), 0, stream>>>(Xsp, Wb, out, (int)Mrows, Nout, K);
    }
}